// Round 1
// baseline (297.664 us; speedup 1.0000x reference)
//
#include <hip/hip_runtime.h>
#include <math.h>

#define N_PTS   65536
#define BATCH   2
#define TOTAL   (BATCH * N_PTS)   // 131072
#define NPACK   48                // floats per point, neighbor payload
#define CPACK   12                // floats per point, center payload
#define EPSB    1e-5f

// ---------------------------------------------------------------------------
// Kernel 1: per-point precompute.
//   packN[j] = { x, y, z, Mdot, Bn'[0..7], G[0..31], pad[4] }   (48 f)
//   packC[j] = { x, y, z, etadot, A'[0..7] }                    (12 f)
// ---------------------------------------------------------------------------
__global__ __launch_bounds__(256) void k1_precompute(
    const float* __restrict__ feats,   // [TOTAL][35]
    const float* __restrict__ pW,      // point_W  [10][8]
    const float* __restrict__ pBN,     // point_bn [4][8]
    const float* __restrict__ eW,      // eta_W    [32][8]
    const float* __restrict__ eBN,     // eta_bn   [4][8]
    const float* __restrict__ mW,      // mu_W     [32][8]
    const float* __restrict__ mBN,     // mu_bn    [4][8]
    const float* __restrict__ gW,      // gamma_W  [35][32]
    const float* __restrict__ gBN,     // gamma_bn [4][32]
    const float* __restrict__ mapW,    // map_W    [24]
    float* __restrict__ packN,
    float* __restrict__ packC)
{
    const int j = blockIdx.x * 256 + threadIdx.x;

    float f[35];
    const float* row = feats + j * 35;
#pragma unroll
    for (int d = 0; d < 35; ++d) f[d] = row[d];

    const float x = f[0], y = f[1], z = f[2];
    const float pp = x * x + y * y + z * z;

    // ---- G = bn(f @ gamma_W) -------------------------------------------
    float G[32];
#pragma unroll
    for (int q = 0; q < 32; ++q) G[q] = 0.f;
#pragma unroll
    for (int d = 0; d < 35; ++d) {
        const float fd = f[d];
#pragma unroll
        for (int q = 0; q < 32; ++q) G[q] = fmaf(fd, gW[d * 32 + q], G[q]);
    }
#pragma unroll
    for (int q = 0; q < 32; ++q) {
        const float g = gBN[q], b = gBN[32 + q], m = gBN[64 + q], v = gBN[96 + q];
        const float s = g / sqrtf(v + EPSB);
        G[q] = fmaf(G[q], s, b - m * s);
    }

    // ---- eta / mu (8ch) -> scalar dots with map_W ----------------------
    float eta[8], mu[8];
#pragma unroll
    for (int q = 0; q < 8; ++q) { eta[q] = 0.f; mu[q] = 0.f; }
#pragma unroll
    for (int i = 0; i < 32; ++i) {
        const float fi = f[3 + i];
#pragma unroll
        for (int q = 0; q < 8; ++q) {
            eta[q] = fmaf(fi, eW[i * 8 + q], eta[q]);
            mu[q]  = fmaf(fi, mW[i * 8 + q], mu[q]);
        }
    }
    float etadot = 0.f, Mdot = 0.f;
#pragma unroll
    for (int q = 0; q < 8; ++q) {
        const float ge = eBN[q], be = eBN[8 + q], me = eBN[16 + q], ve = eBN[24 + q];
        const float se = ge / sqrtf(ve + EPSB);
        etadot = fmaf(fmaf(eta[q], se, be - me * se), mapW[8 + q], etadot);
        const float gm = mBN[q], bm = mBN[8 + q], mm = mBN[16 + q], vm = mBN[24 + q];
        const float sm = gm / sqrtf(vm + EPSB);
        Mdot = fmaf(fmaf(mu[q], sm, bm - mm * sm), mapW[16 + q], Mdot);
    }

    // ---- point branch split: neighbor part Bn', center part A' ---------
    // point_lin[c] = d2*pW0 + p.(pW1:4+pW7:10) + pn.(pW4:7-pW7:10)
    // d2 = |p|^2 - 2 p.pn + |pn|^2
    float Bnp[8], Ap[8];
#pragma unroll
    for (int q = 0; q < 8; ++q) {
        const float pw0 = pW[q];
        const float g = pBN[q], b = pBN[8 + q], m = pBN[16 + q], v = pBN[24 + q];
        const float s = g / sqrtf(v + EPSB);
        const float t = b - m * s;
        const float Braw = pp * pw0
            + x * (pW[32 + q] - pW[56 + q])
            + y * (pW[40 + q] - pW[64 + q])
            + z * (pW[48 + q] - pW[72 + q]);
        const float Araw = pp * pw0
            + x * (pW[8 + q]  + pW[56 + q])
            + y * (pW[16 + q] + pW[64 + q])
            + z * (pW[24 + q] + pW[72 + q]);
        Bnp[q] = Braw * s;
        Ap[q]  = fmaf(Araw, s, t);
    }

    // ---- stores --------------------------------------------------------
    float4* PN = (float4*)(packN + j * NPACK);
    PN[0] = make_float4(x, y, z, Mdot);
    PN[1] = make_float4(Bnp[0], Bnp[1], Bnp[2], Bnp[3]);
    PN[2] = make_float4(Bnp[4], Bnp[5], Bnp[6], Bnp[7]);
#pragma unroll
    for (int q = 0; q < 8; ++q)
        PN[3 + q] = make_float4(G[q * 4], G[q * 4 + 1], G[q * 4 + 2], G[q * 4 + 3]);

    float4* PC = (float4*)(packC + j * CPACK);
    PC[0] = make_float4(x, y, z, etadot);
    PC[1] = make_float4(Ap[0], Ap[1], Ap[2], Ap[3]);
    PC[2] = make_float4(Ap[4], Ap[5], Ap[6], Ap[7]);
}

// ---------------------------------------------------------------------------
// Kernel 2: per-center gather + gate + max-pool -> pooled[c][32]
// ---------------------------------------------------------------------------
__global__ __launch_bounds__(256) void k2_aggregate(
    const int* __restrict__ idx,      // [TOTAL][16]
    const float* __restrict__ packN,
    const float* __restrict__ packC,
    const float* __restrict__ pW,     // point_W
    const float* __restrict__ pBN,    // point_bn
    const float* __restrict__ mapW,   // [24]
    const float* __restrict__ mapBN,  // [4]
    float* __restrict__ pooled)       // [TOTAL][32]
{
    const int c = blockIdx.x * 256 + threadIdx.x;

    // fold map bn
    float ms, mt;
    {
        const float g = mapBN[0], b = mapBN[1], m = mapBN[2], v = mapBN[3];
        ms = g / sqrtf(v + EPSB);
        mt = b - m * ms;
    }
    // W0'[c] = 2*pW0[c]*point_scale[c]; mW0 = map_W[0:8]
    float W0p[8], mW0[8];
#pragma unroll
    for (int q = 0; q < 8; ++q) {
        const float g = pBN[q], v = pBN[24 + q];
        const float s = g / sqrtf(v + EPSB);
        W0p[q] = 2.f * pW[q] * s;
        mW0[q] = mapW[q];
    }

    const float4* PC = (const float4*)(packC + c * CPACK);
    const float4 c0 = PC[0], c1 = PC[1], c2 = PC[2];
    const float px = c0.x, py = c0.y, pz = c0.z, etadot = c0.w;
    const float Ap[8] = { c1.x, c1.y, c1.z, c1.w, c2.x, c2.y, c2.z, c2.w };

    const int* ib = idx + c * 16;
    const int bbase = c & ~(N_PTS - 1);   // b * N

    float o32[32];
#pragma unroll
    for (int q = 0; q < 32; ++q) o32[q] = -INFINITY;

#pragma unroll 4
    for (int k = 0; k < 16; ++k) {
        const int gj = bbase + ib[k];
        const float4* P = (const float4*)(packN + gj * NPACK);
        const float4 h  = P[0];           // x, y, z, Mdot
        const float4 b0 = P[1], b1 = P[2];
        const float dot3 = px * h.x + py * h.y + pz * h.z;
        const float Bn[8] = { b0.x, b0.y, b0.z, b0.w, b1.x, b1.y, b1.z, b1.w };
        float pd = 0.f;
#pragma unroll
        for (int q = 0; q < 8; ++q) {
            const float u = Ap[q] + Bn[q] - dot3 * W0p[q];
            pd = fmaf(fmaxf(u, 0.f), mW0[q], pd);
        }
        float s = fmaf(pd + etadot + h.w, ms, mt);
        s = fmaxf(s, 0.f);
#pragma unroll
        for (int q = 0; q < 8; ++q) {
            const float4 gv = P[3 + q];
            o32[q * 4 + 0] = fmaxf(o32[q * 4 + 0], s * gv.x);
            o32[q * 4 + 1] = fmaxf(o32[q * 4 + 1], s * gv.y);
            o32[q * 4 + 2] = fmaxf(o32[q * 4 + 2], s * gv.z);
            o32[q * 4 + 3] = fmaxf(o32[q * 4 + 3], s * gv.w);
        }
    }

    float4* OP = (float4*)(pooled + c * 32);
#pragma unroll
    for (int q = 0; q < 8; ++q)
        OP[q] = make_float4(o32[q * 4], o32[q * 4 + 1], o32[q * 4 + 2], o32[q * 4 + 3]);
}

// ---------------------------------------------------------------------------
// Kernel 3: fc — (TOTAL x 32) @ (32 x 128).
// Lane owns an output column o; pooled row address is wave-uniform -> s_load.
// ---------------------------------------------------------------------------
#define CPB 128   // centers per block
__global__ __launch_bounds__(256) void k3_fc(
    const float* __restrict__ pooled,  // [TOTAL][32]
    const float* __restrict__ fcW,     // [32][128]
    float* __restrict__ out)           // [TOTAL][128]
{
    const int tid = threadIdx.x;
    const int o = tid & 127;
    const int g = tid >> 7;    // 0..1
    float w[32];
#pragma unroll
    for (int k = 0; k < 32; ++k) w[k] = fcW[k * 128 + o];

    const int base = blockIdx.x * CPB;
    for (int cl = g; cl < CPB; cl += 2) {
        const float* r = pooled + (base + cl) * 32;   // wave-uniform address
        float acc = 0.f;
#pragma unroll
        for (int k = 0; k < 32; ++k) acc = fmaf(r[k], w[k], acc);
        out[(base + cl) * 128 + o] = acc;
    }
}

// ---------------------------------------------------------------------------
extern "C" void kernel_launch(void* const* d_in, const int* in_sizes, int n_in,
                              void* d_out, int out_size, void* d_ws, size_t ws_size,
                              hipStream_t stream) {
    const float* feats    = (const float*)d_in[0];
    const int*   idx      = (const int*)  d_in[1];
    const float* point_W  = (const float*)d_in[2];
    const float* point_bn = (const float*)d_in[3];
    const float* eta_W    = (const float*)d_in[4];
    const float* eta_bn   = (const float*)d_in[5];
    const float* mu_W     = (const float*)d_in[6];
    const float* mu_bn    = (const float*)d_in[7];
    const float* gamma_W  = (const float*)d_in[8];
    const float* gamma_bn = (const float*)d_in[9];
    const float* map_W    = (const float*)d_in[10];
    const float* map_bn   = (const float*)d_in[11];
    const float* fc_W     = (const float*)d_in[12];
    float* out = (float*)d_out;

    float* packN  = (float*)d_ws;                 // TOTAL*48 f = 25.2 MB
    float* packC  = packN + (size_t)TOTAL * NPACK; // TOTAL*12 f = 6.3 MB
    float* pooled = packC + (size_t)TOTAL * CPACK; // TOTAL*32 f = 16.8 MB

    hipLaunchKernelGGL(k1_precompute, dim3(TOTAL / 256), dim3(256), 0, stream,
                       feats, point_W, point_bn, eta_W, eta_bn, mu_W, mu_bn,
                       gamma_W, gamma_bn, map_W, packN, packC);
    hipLaunchKernelGGL(k2_aggregate, dim3(TOTAL / 256), dim3(256), 0, stream,
                       idx, packN, packC, point_W, point_bn, map_W, map_bn,
                       pooled);
    hipLaunchKernelGGL(k3_fc, dim3(TOTAL / CPB), dim3(256), 0, stream,
                       pooled, fc_W, out);
}

// Round 2
// 251.082 us; speedup vs baseline: 1.1855x; 1.1855x over previous
//
#include <hip/hip_runtime.h>
#include <hip/hip_fp16.h>
#include <math.h>

#define N_PTS   65536
#define BATCH   2
#define TOTAL   (BATCH * N_PTS)   // 131072
#define NPACK   24                // floats per point, neighbor payload (96 B)
#define CPACK   12                // floats per point, center payload
#define EPSB    1e-5f

// ---------------------------------------------------------------------------
// Kernel 1: per-point precompute.
//   packN[j] (96 B) = { x,y,z,Mdot (f32) | Bn'[0..7] (f16) | G[0..31] (f16) }
//   packC[j] (48 B) = { x,y,z,etadot (f32) | A'[0..7] (f32) }
// ---------------------------------------------------------------------------
__global__ __launch_bounds__(256) void k1_precompute(
    const float* __restrict__ feats,   // [TOTAL][35]
    const float* __restrict__ pW,      // point_W  [10][8]
    const float* __restrict__ pBN,     // point_bn [4][8]
    const float* __restrict__ eW,      // eta_W    [32][8]
    const float* __restrict__ eBN,     // eta_bn   [4][8]
    const float* __restrict__ mW,      // mu_W     [32][8]
    const float* __restrict__ mBN,     // mu_bn    [4][8]
    const float* __restrict__ gW,      // gamma_W  [35][32]
    const float* __restrict__ gBN,     // gamma_bn [4][32]
    const float* __restrict__ mapW,    // map_W    [24]
    float* __restrict__ packN,
    float* __restrict__ packC)
{
    const int j = blockIdx.x * 256 + threadIdx.x;

    float f[35];
    const float* row = feats + j * 35;
#pragma unroll
    for (int d = 0; d < 35; ++d) f[d] = row[d];

    const float x = f[0], y = f[1], z = f[2];
    const float pp = x * x + y * y + z * z;

    // ---- G = bn(f @ gamma_W) -------------------------------------------
    float G[32];
#pragma unroll
    for (int q = 0; q < 32; ++q) G[q] = 0.f;
#pragma unroll
    for (int d = 0; d < 35; ++d) {
        const float fd = f[d];
#pragma unroll
        for (int q = 0; q < 32; ++q) G[q] = fmaf(fd, gW[d * 32 + q], G[q]);
    }
#pragma unroll
    for (int q = 0; q < 32; ++q) {
        const float g = gBN[q], b = gBN[32 + q], m = gBN[64 + q], v = gBN[96 + q];
        const float s = g / sqrtf(v + EPSB);
        G[q] = fmaf(G[q], s, b - m * s);
    }

    // ---- eta / mu (8ch) -> scalar dots with map_W ----------------------
    float eta[8], mu[8];
#pragma unroll
    for (int q = 0; q < 8; ++q) { eta[q] = 0.f; mu[q] = 0.f; }
#pragma unroll
    for (int i = 0; i < 32; ++i) {
        const float fi = f[3 + i];
#pragma unroll
        for (int q = 0; q < 8; ++q) {
            eta[q] = fmaf(fi, eW[i * 8 + q], eta[q]);
            mu[q]  = fmaf(fi, mW[i * 8 + q], mu[q]);
        }
    }
    float etadot = 0.f, Mdot = 0.f;
#pragma unroll
    for (int q = 0; q < 8; ++q) {
        const float ge = eBN[q], be = eBN[8 + q], me = eBN[16 + q], ve = eBN[24 + q];
        const float se = ge / sqrtf(ve + EPSB);
        etadot = fmaf(fmaf(eta[q], se, be - me * se), mapW[8 + q], etadot);
        const float gm = mBN[q], bm = mBN[8 + q], mm = mBN[16 + q], vm = mBN[24 + q];
        const float sm = gm / sqrtf(vm + EPSB);
        Mdot = fmaf(fmaf(mu[q], sm, bm - mm * sm), mapW[16 + q], Mdot);
    }

    // ---- point branch split: neighbor part Bn', center part A' ---------
    float Bnp[8], Ap[8];
#pragma unroll
    for (int q = 0; q < 8; ++q) {
        const float pw0 = pW[q];
        const float g = pBN[q], b = pBN[8 + q], m = pBN[16 + q], v = pBN[24 + q];
        const float s = g / sqrtf(v + EPSB);
        const float t = b - m * s;
        const float Braw = pp * pw0
            + x * (pW[32 + q] - pW[56 + q])
            + y * (pW[40 + q] - pW[64 + q])
            + z * (pW[48 + q] - pW[72 + q]);
        const float Araw = pp * pw0
            + x * (pW[8 + q]  + pW[56 + q])
            + y * (pW[16 + q] + pW[64 + q])
            + z * (pW[24 + q] + pW[72 + q]);
        Bnp[q] = Braw * s;
        Ap[q]  = fmaf(Araw, s, t);
    }

    // ---- stores --------------------------------------------------------
    float4* PN = (float4*)(packN + (size_t)j * NPACK);
    PN[0] = make_float4(x, y, z, Mdot);
    {
        float4 b4;
        __half2* hb = (__half2*)&b4;
        hb[0] = __floats2half2_rn(Bnp[0], Bnp[1]);
        hb[1] = __floats2half2_rn(Bnp[2], Bnp[3]);
        hb[2] = __floats2half2_rn(Bnp[4], Bnp[5]);
        hb[3] = __floats2half2_rn(Bnp[6], Bnp[7]);
        PN[1] = b4;
    }
#pragma unroll
    for (int q = 0; q < 4; ++q) {
        float4 g4;
        __half2* hg = (__half2*)&g4;
        hg[0] = __floats2half2_rn(G[q * 8 + 0], G[q * 8 + 1]);
        hg[1] = __floats2half2_rn(G[q * 8 + 2], G[q * 8 + 3]);
        hg[2] = __floats2half2_rn(G[q * 8 + 4], G[q * 8 + 5]);
        hg[3] = __floats2half2_rn(G[q * 8 + 6], G[q * 8 + 7]);
        PN[2 + q] = g4;
    }

    float4* PC = (float4*)(packC + (size_t)j * CPACK);
    PC[0] = make_float4(x, y, z, etadot);
    PC[1] = make_float4(Ap[0], Ap[1], Ap[2], Ap[3]);
    PC[2] = make_float4(Ap[4], Ap[5], Ap[6], Ap[7]);
}

// ---------------------------------------------------------------------------
// Kernel 2: gather + gate + max-pool. 4 threads per center, 4 neighbors each,
// quad shfl-xor max reduce. pooled[c][32]
// ---------------------------------------------------------------------------
__global__ __launch_bounds__(256) void k2_aggregate(
    const int* __restrict__ idx,      // [TOTAL][16]
    const float* __restrict__ packN,
    const float* __restrict__ packC,
    const float* __restrict__ pW,     // point_W
    const float* __restrict__ pBN,    // point_bn
    const float* __restrict__ mapW,   // [24]
    const float* __restrict__ mapBN,  // [4]
    float* __restrict__ pooled)       // [TOTAL][32]
{
    const int tid = threadIdx.x;
    const int c  = blockIdx.x * 64 + (tid >> 2);
    const int ks = tid & 3;

    // fold map bn
    float ms, mt;
    {
        const float g = mapBN[0], b = mapBN[1], m = mapBN[2], v = mapBN[3];
        ms = g / sqrtf(v + EPSB);
        mt = b - m * ms;
    }
    float W0p[8], mW0[8];
#pragma unroll
    for (int q = 0; q < 8; ++q) {
        const float g = pBN[q], v = pBN[24 + q];
        const float s = g / sqrtf(v + EPSB);
        W0p[q] = 2.f * pW[q] * s;
        mW0[q] = mapW[q];
    }

    const float4* PC = (const float4*)(packC + (size_t)c * CPACK);
    const float4 c0 = PC[0], c1 = PC[1], c2 = PC[2];
    const float px = c0.x, py = c0.y, pz = c0.z, etadot = c0.w;
    const float Ap[8] = { c1.x, c1.y, c1.z, c1.w, c2.x, c2.y, c2.z, c2.w };

    const int4 ib4 = ((const int4*)idx)[c * 4 + ks];
    const int nbr[4] = { ib4.x, ib4.y, ib4.z, ib4.w };
    const int bbase = c & ~(N_PTS - 1);   // b * N

    float o32[32];
#pragma unroll
    for (int q = 0; q < 32; ++q) o32[q] = -INFINITY;

#pragma unroll
    for (int k = 0; k < 4; ++k) {
        const int gj = bbase + nbr[k];
        const float4* P = (const float4*)(packN + (size_t)gj * NPACK);
        const float4 h  = P[0];           // x, y, z, Mdot
        const float4 b4 = P[1];
        const float4 g0 = P[2], g1 = P[3], g2 = P[4], g3 = P[5];

        const float dot3 = px * h.x + py * h.y + pz * h.z;
        const __half2* hb = (const __half2*)&b4;
        float pd = 0.f;
#pragma unroll
        for (int q = 0; q < 4; ++q) {
            const float2 bn2 = __half22float2(hb[q]);
            const float u0 = Ap[2 * q]     + bn2.x - dot3 * W0p[2 * q];
            const float u1 = Ap[2 * q + 1] + bn2.y - dot3 * W0p[2 * q + 1];
            pd = fmaf(fmaxf(u0, 0.f), mW0[2 * q], pd);
            pd = fmaf(fmaxf(u1, 0.f), mW0[2 * q + 1], pd);
        }
        float s = fmaf(pd + etadot + h.w, ms, mt);
        s = fmaxf(s, 0.f);

        const float4 gs[4] = { g0, g1, g2, g3 };
#pragma unroll
        for (int q = 0; q < 4; ++q) {
            const __half2* hg = (const __half2*)&gs[q];
#pragma unroll
            for (int r = 0; r < 4; ++r) {
                const float2 g2f = __half22float2(hg[r]);
                o32[q * 8 + r * 2]     = fmaxf(o32[q * 8 + r * 2],     s * g2f.x);
                o32[q * 8 + r * 2 + 1] = fmaxf(o32[q * 8 + r * 2 + 1], s * g2f.y);
            }
        }
    }

    // quad max-reduce (lanes 4g..4g+3 hold the same center)
#pragma unroll
    for (int q = 0; q < 32; ++q) {
        float v = o32[q];
        v = fmaxf(v, __shfl_xor(v, 1));
        v = fmaxf(v, __shfl_xor(v, 2));
        o32[q] = v;
    }

    // each lane writes 2 of the 8 float4 chunks
    float4* OP = (float4*)(pooled + (size_t)c * 32);
    const int q0 = 2 * ks, q1 = 2 * ks + 1;
    OP[q0] = make_float4(o32[q0 * 4], o32[q0 * 4 + 1], o32[q0 * 4 + 2], o32[q0 * 4 + 3]);
    OP[q1] = make_float4(o32[q1 * 4], o32[q1 * 4 + 1], o32[q1 * 4 + 2], o32[q1 * 4 + 3]);
}

// ---------------------------------------------------------------------------
// Kernel 3: fc — (TOTAL x 32) @ (32 x 128).
// Lane owns an output column o; pooled row address is wave-uniform -> s_load.
// ---------------------------------------------------------------------------
#define CPB 128   // centers per block
__global__ __launch_bounds__(256) void k3_fc(
    const float* __restrict__ pooled,  // [TOTAL][32]
    const float* __restrict__ fcW,     // [32][128]
    float* __restrict__ out)           // [TOTAL][128]
{
    const int tid = threadIdx.x;
    const int o = tid & 127;
    const int g = tid >> 7;    // 0..1
    float w[32];
#pragma unroll
    for (int k = 0; k < 32; ++k) w[k] = fcW[k * 128 + o];

    const int base = blockIdx.x * CPB;
    for (int cl = g; cl < CPB; cl += 2) {
        const float* r = pooled + (size_t)(base + cl) * 32;   // wave-uniform
        float acc = 0.f;
#pragma unroll
        for (int k = 0; k < 32; ++k) acc = fmaf(r[k], w[k], acc);
        out[(size_t)(base + cl) * 128 + o] = acc;
    }
}

// ---------------------------------------------------------------------------
extern "C" void kernel_launch(void* const* d_in, const int* in_sizes, int n_in,
                              void* d_out, int out_size, void* d_ws, size_t ws_size,
                              hipStream_t stream) {
    const float* feats    = (const float*)d_in[0];
    const int*   idx      = (const int*)  d_in[1];
    const float* point_W  = (const float*)d_in[2];
    const float* point_bn = (const float*)d_in[3];
    const float* eta_W    = (const float*)d_in[4];
    const float* eta_bn   = (const float*)d_in[5];
    const float* mu_W     = (const float*)d_in[6];
    const float* mu_bn    = (const float*)d_in[7];
    const float* gamma_W  = (const float*)d_in[8];
    const float* gamma_bn = (const float*)d_in[9];
    const float* map_W    = (const float*)d_in[10];
    const float* map_bn   = (const float*)d_in[11];
    const float* fc_W     = (const float*)d_in[12];
    float* out = (float*)d_out;

    float* packN  = (float*)d_ws;                  // TOTAL*24 f = 12.6 MB
    float* packC  = packN + (size_t)TOTAL * NPACK; // TOTAL*12 f =  6.3 MB
    float* pooled = packC + (size_t)TOTAL * CPACK; // TOTAL*32 f = 16.8 MB

    hipLaunchKernelGGL(k1_precompute, dim3(TOTAL / 256), dim3(256), 0, stream,
                       feats, point_W, point_bn, eta_W, eta_bn, mu_W, mu_bn,
                       gamma_W, gamma_bn, map_W, packN, packC);
    hipLaunchKernelGGL(k2_aggregate, dim3(TOTAL * 4 / 256), dim3(256), 0, stream,
                       idx, packN, packC, point_W, point_bn, map_W, map_bn,
                       pooled);
    hipLaunchKernelGGL(k3_fc, dim3(TOTAL / CPB), dim3(256), 0, stream,
                       pooled, fc_W, out);
}

// Round 4
// 186.412 us; speedup vs baseline: 1.5968x; 1.3469x over previous
//
#include <hip/hip_runtime.h>
#include <hip/hip_fp16.h>
#include <math.h>

#define N_PTS   65536
#define BATCH   2
#define TOTAL   (BATCH * N_PTS)   // 131072
#define NPACK   24                // floats per point, neighbor payload (96 B)
#define CPACK   12                // floats per point, center payload
#define EPSB    1e-5f

// ---------------------------------------------------------------------------
// Kernel 1: per-point precompute. Weights + feats tile staged in LDS.
//   packN[j] (96 B) = { x,y,z,Mdot (f32) | Bn'[0..7] (f16) | G[0..31] (f16) }
//   packC[j] (48 B) = { x,y,z,etadot (f32) | A'[0..7] (f32) }
// ---------------------------------------------------------------------------
__global__ __launch_bounds__(256) void k1_precompute(
    const float* __restrict__ feats,   // [TOTAL][35]
    const float* __restrict__ pW,      // point_W  [10][8]
    const float* __restrict__ pBN,     // point_bn [4][8]
    const float* __restrict__ eW,      // eta_W    [32][8]
    const float* __restrict__ eBN,     // eta_bn   [4][8]
    const float* __restrict__ mW,      // mu_W     [32][8]
    const float* __restrict__ mBN,     // mu_bn    [4][8]
    const float* __restrict__ gW,      // gamma_W  [35][32]
    const float* __restrict__ gBN,     // gamma_bn [4][32]
    const float* __restrict__ mapW,    // map_W    [24]
    float* __restrict__ packN,
    float* __restrict__ packC)
{
    __shared__ float sG[35 * 32];      // gamma_W
    __shared__ float sE[32 * 8];       // eta_W
    __shared__ float sM[32 * 8];       // mu_W
    __shared__ float sF[256 * 35];     // feats tile

    const int tid = threadIdx.x;
    const int base = blockIdx.x * 256;

    // ---- stage weights + feats (coalesced) -----------------------------
    for (int i = tid; i < 35 * 32; i += 256) sG[i] = gW[i];
    if (tid < 256) { sE[tid] = eW[tid]; sM[tid] = mW[tid]; }
#pragma unroll
    for (int t = 0; t < 35; ++t)
        sF[t * 256 + tid] = feats[(size_t)base * 35 + t * 256 + tid];
    __syncthreads();

    const float* f = sF + tid * 35;    // this thread's row (bank-stride 3: free)
    const float x = f[0], y = f[1], z = f[2];
    const float pp = x * x + y * y + z * z;

    // ---- G = bn(f @ gamma_W) -------------------------------------------
    float G[32];
#pragma unroll
    for (int q = 0; q < 32; ++q) G[q] = 0.f;
#pragma unroll 4
    for (int d = 0; d < 35; ++d) {
        const float fd = f[d];
        const float4* w4 = (const float4*)(sG + d * 32);  // broadcast reads
#pragma unroll
        for (int q4 = 0; q4 < 8; ++q4) {
            const float4 w = w4[q4];
            G[q4 * 4 + 0] = fmaf(fd, w.x, G[q4 * 4 + 0]);
            G[q4 * 4 + 1] = fmaf(fd, w.y, G[q4 * 4 + 1]);
            G[q4 * 4 + 2] = fmaf(fd, w.z, G[q4 * 4 + 2]);
            G[q4 * 4 + 3] = fmaf(fd, w.w, G[q4 * 4 + 3]);
        }
    }
#pragma unroll
    for (int q = 0; q < 32; ++q) {
        const float g = gBN[q], b = gBN[32 + q], m = gBN[64 + q], v = gBN[96 + q];
        const float s = g / sqrtf(v + EPSB);
        G[q] = fmaf(G[q], s, b - m * s);
    }

    // ---- eta / mu (8ch) -> scalar dots with map_W ----------------------
    float eta[8], mu[8];
#pragma unroll
    for (int q = 0; q < 8; ++q) { eta[q] = 0.f; mu[q] = 0.f; }
#pragma unroll 4
    for (int i = 0; i < 32; ++i) {
        const float fi = f[3 + i];
        const float4* e4 = (const float4*)(sE + i * 8);
        const float4* m4 = (const float4*)(sM + i * 8);
#pragma unroll
        for (int h = 0; h < 2; ++h) {
            const float4 we = e4[h], wm = m4[h];
            eta[h * 4 + 0] = fmaf(fi, we.x, eta[h * 4 + 0]);
            eta[h * 4 + 1] = fmaf(fi, we.y, eta[h * 4 + 1]);
            eta[h * 4 + 2] = fmaf(fi, we.z, eta[h * 4 + 2]);
            eta[h * 4 + 3] = fmaf(fi, we.w, eta[h * 4 + 3]);
            mu[h * 4 + 0] = fmaf(fi, wm.x, mu[h * 4 + 0]);
            mu[h * 4 + 1] = fmaf(fi, wm.y, mu[h * 4 + 1]);
            mu[h * 4 + 2] = fmaf(fi, wm.z, mu[h * 4 + 2]);
            mu[h * 4 + 3] = fmaf(fi, wm.w, mu[h * 4 + 3]);
        }
    }
    float etadot = 0.f, Mdot = 0.f;
#pragma unroll
    for (int q = 0; q < 8; ++q) {
        const float ge = eBN[q], be = eBN[8 + q], me = eBN[16 + q], ve = eBN[24 + q];
        const float se = ge / sqrtf(ve + EPSB);
        etadot = fmaf(fmaf(eta[q], se, be - me * se), mapW[8 + q], etadot);
        const float gm = mBN[q], bm = mBN[8 + q], mm = mBN[16 + q], vm = mBN[24 + q];
        const float sm = gm / sqrtf(vm + EPSB);
        Mdot = fmaf(fmaf(mu[q], sm, bm - mm * sm), mapW[16 + q], Mdot);
    }

    // ---- point branch split: neighbor part Bn', center part A' ---------
    float Bnp[8], Ap[8];
#pragma unroll
    for (int q = 0; q < 8; ++q) {
        const float pw0 = pW[q];
        const float g = pBN[q], b = pBN[8 + q], m = pBN[16 + q], v = pBN[24 + q];
        const float s = g / sqrtf(v + EPSB);
        const float t = b - m * s;
        const float Braw = pp * pw0
            + x * (pW[32 + q] - pW[56 + q])
            + y * (pW[40 + q] - pW[64 + q])
            + z * (pW[48 + q] - pW[72 + q]);
        const float Araw = pp * pw0
            + x * (pW[8 + q]  + pW[56 + q])
            + y * (pW[16 + q] + pW[64 + q])
            + z * (pW[24 + q] + pW[72 + q]);
        Bnp[q] = Braw * s;
        Ap[q]  = fmaf(Araw, s, t);
    }

    // ---- stores --------------------------------------------------------
    const int j = base + tid;
    float4* PN = (float4*)(packN + (size_t)j * NPACK);
    PN[0] = make_float4(x, y, z, Mdot);
    {
        float4 b4;
        __half2* hb = (__half2*)&b4;
        hb[0] = __floats2half2_rn(Bnp[0], Bnp[1]);
        hb[1] = __floats2half2_rn(Bnp[2], Bnp[3]);
        hb[2] = __floats2half2_rn(Bnp[4], Bnp[5]);
        hb[3] = __floats2half2_rn(Bnp[6], Bnp[7]);
        PN[1] = b4;
    }
#pragma unroll
    for (int q = 0; q < 4; ++q) {
        float4 g4;
        __half2* hg = (__half2*)&g4;
        hg[0] = __floats2half2_rn(G[q * 8 + 0], G[q * 8 + 1]);
        hg[1] = __floats2half2_rn(G[q * 8 + 2], G[q * 8 + 3]);
        hg[2] = __floats2half2_rn(G[q * 8 + 4], G[q * 8 + 5]);
        hg[3] = __floats2half2_rn(G[q * 8 + 6], G[q * 8 + 7]);
        PN[2 + q] = g4;
    }

    float4* PC = (float4*)(packC + (size_t)j * CPACK);
    PC[0] = make_float4(x, y, z, etadot);
    PC[1] = make_float4(Ap[0], Ap[1], Ap[2], Ap[3]);
    PC[2] = make_float4(Ap[4], Ap[5], Ap[6], Ap[7]);
}

// ---------------------------------------------------------------------------
// Kernel 2 (fused): gather + gate + max-pool + fc. 8 threads/center,
// 32 centers/block, pooled tile lives in LDS, fc phase writes out directly.
// ---------------------------------------------------------------------------
__global__ __launch_bounds__(256) void k2_aggregate_fc(
    const int* __restrict__ idx,      // [TOTAL][16]
    const float* __restrict__ packN,
    const float* __restrict__ packC,
    const float* __restrict__ pW,     // point_W
    const float* __restrict__ pBN,    // point_bn
    const float* __restrict__ mapW,   // [24]
    const float* __restrict__ mapBN,  // [4]
    const float* __restrict__ fcW,    // [32][128]
    float* __restrict__ out)          // [TOTAL][128]
{
    __shared__ float sP[32 * 32];     // pooled tile, 4 KB

    const int tid = threadIdx.x;
    const int cl  = tid >> 3;         // local center 0..31
    const int ks  = tid & 7;          // neighbor-slot group
    const int cbase = blockIdx.x * 32;
    const int c = cbase + cl;

    // fold map bn
    float ms, mt;
    {
        const float g = mapBN[0], b = mapBN[1], m = mapBN[2], v = mapBN[3];
        ms = g / sqrtf(v + EPSB);
        mt = b - m * ms;
    }
    float W0p[8], mW0[8];
#pragma unroll
    for (int q = 0; q < 8; ++q) {
        const float g = pBN[q], v = pBN[24 + q];
        const float s = g / sqrtf(v + EPSB);
        W0p[q] = 2.f * pW[q] * s;
        mW0[q] = mapW[q];
    }

    const float4* PC = (const float4*)(packC + (size_t)c * CPACK);
    const float4 c0 = PC[0], c1 = PC[1], c2 = PC[2];
    const float px = c0.x, py = c0.y, pz = c0.z, etadot = c0.w;
    const float Ap[8] = { c1.x, c1.y, c1.z, c1.w, c2.x, c2.y, c2.z, c2.w };

    const int2 ib2 = ((const int2*)idx)[c * 8 + ks];
    const int nbr[2] = { ib2.x, ib2.y };
    const int bbase = c & ~(N_PTS - 1);   // b * N

    float o32[32];
#pragma unroll
    for (int q = 0; q < 32; ++q) o32[q] = -INFINITY;

#pragma unroll
    for (int k = 0; k < 2; ++k) {
        const int gj = bbase + nbr[k];
        const float4* P = (const float4*)(packN + (size_t)gj * NPACK);
        const float4 h  = P[0];           // x, y, z, Mdot
        const float4 b4 = P[1];
        const float4 g0 = P[2], g1 = P[3], g2 = P[4], g3 = P[5];

        const float dot3 = px * h.x + py * h.y + pz * h.z;
        const __half2* hb = (const __half2*)&b4;
        float pd = 0.f;
#pragma unroll
        for (int q = 0; q < 4; ++q) {
            const float2 bn2 = __half22float2(hb[q]);
            const float u0 = Ap[2 * q]     + bn2.x - dot3 * W0p[2 * q];
            const float u1 = Ap[2 * q + 1] + bn2.y - dot3 * W0p[2 * q + 1];
            pd = fmaf(fmaxf(u0, 0.f), mW0[2 * q], pd);
            pd = fmaf(fmaxf(u1, 0.f), mW0[2 * q + 1], pd);
        }
        float s = fmaf(pd + etadot + h.w, ms, mt);
        s = fmaxf(s, 0.f);

        const float4 gs[4] = { g0, g1, g2, g3 };
#pragma unroll
        for (int q = 0; q < 4; ++q) {
            const __half2* hg = (const __half2*)&gs[q];
#pragma unroll
            for (int r = 0; r < 4; ++r) {
                const float2 g2f = __half22float2(hg[r]);
                o32[q * 8 + r * 2]     = fmaxf(o32[q * 8 + r * 2],     s * g2f.x);
                o32[q * 8 + r * 2 + 1] = fmaxf(o32[q * 8 + r * 2 + 1], s * g2f.y);
            }
        }
    }

    // 8-lane max-reduce (all 8 lanes end with the full reduction)
#pragma unroll
    for (int q = 0; q < 32; ++q) {
        float v = o32[q];
        v = fmaxf(v, __shfl_xor(v, 1));
        v = fmaxf(v, __shfl_xor(v, 2));
        v = fmaxf(v, __shfl_xor(v, 4));
        o32[q] = v;
    }

    // lane ks writes float4 chunk ks of this center's pooled row
    {
        float4* row = (float4*)(sP + cl * 32);
        row[ks] = make_float4(o32[ks * 4], o32[ks * 4 + 1],
                              o32[ks * 4 + 2], o32[ks * 4 + 3]);
    }

    // ---- fc phase ------------------------------------------------------
    const int o = tid & 127;
    const int g = tid >> 7;    // 0..1
    float w[32];
#pragma unroll
    for (int k = 0; k < 32; ++k) w[k] = fcW[k * 128 + o];
    __syncthreads();

#pragma unroll 2
    for (int r = g; r < 32; r += 2) {
        const float4* rp = (const float4*)(sP + r * 32);  // broadcast reads
        float acc = 0.f;
#pragma unroll
        for (int k4 = 0; k4 < 8; ++k4) {
            const float4 rv = rp[k4];
            acc = fmaf(rv.x, w[k4 * 4 + 0], acc);
            acc = fmaf(rv.y, w[k4 * 4 + 1], acc);
            acc = fmaf(rv.z, w[k4 * 4 + 2], acc);
            acc = fmaf(rv.w, w[k4 * 4 + 3], acc);
        }
        out[(size_t)(cbase + r) * 128 + o] = acc;
    }
}

// ---------------------------------------------------------------------------
extern "C" void kernel_launch(void* const* d_in, const int* in_sizes, int n_in,
                              void* d_out, int out_size, void* d_ws, size_t ws_size,
                              hipStream_t stream) {
    const float* feats    = (const float*)d_in[0];
    const int*   idx      = (const int*)  d_in[1];
    const float* point_W  = (const float*)d_in[2];
    const float* point_bn = (const float*)d_in[3];
    const float* eta_W    = (const float*)d_in[4];
    const float* eta_bn   = (const float*)d_in[5];
    const float* mu_W     = (const float*)d_in[6];
    const float* mu_bn    = (const float*)d_in[7];
    const float* gamma_W  = (const float*)d_in[8];
    const float* gamma_bn = (const float*)d_in[9];
    const float* map_W    = (const float*)d_in[10];
    const float* map_bn   = (const float*)d_in[11];
    const float* fc_W     = (const float*)d_in[12];
    float* out = (float*)d_out;

    float* packN  = (float*)d_ws;                  // TOTAL*24 f = 12.6 MB
    float* packC  = packN + (size_t)TOTAL * NPACK; // TOTAL*12 f =  6.3 MB

    hipLaunchKernelGGL(k1_precompute, dim3(TOTAL / 256), dim3(256), 0, stream,
                       feats, point_W, point_bn, eta_W, eta_bn, mu_W, mu_bn,
                       gamma_W, gamma_bn, map_W, packN, packC);
    hipLaunchKernelGGL(k2_aggregate_fc, dim3(TOTAL / 32), dim3(256), 0, stream,
                       idx, packN, packC, point_W, point_bn, map_W, map_bn,
                       fc_W, out);
}

// Round 5
// 177.039 us; speedup vs baseline: 1.6813x; 1.0529x over previous
//
#include <hip/hip_runtime.h>
#include <hip/hip_fp16.h>
#include <math.h>

#define N_PTS   65536
#define BATCH   2
#define TOTAL   (BATCH * N_PTS)   // 131072
#define NPACK   24                // floats per point, neighbor payload (96 B)
#define CPACK   12                // floats per point, center payload
#define EPSB    1e-5f

typedef short short8 __attribute__((ext_vector_type(8)));
typedef float f32x4 __attribute__((ext_vector_type(4)));

static __device__ inline short f2bf(float x) {   // RNE f32 -> bf16 bits
    union { float f; unsigned u; } c; c.f = x;
    unsigned r = c.u + 0x7FFF + ((c.u >> 16) & 1);
    return (short)(r >> 16);
}
static __device__ inline unsigned pk_mul(unsigned a, unsigned b) {
    unsigned r; asm("v_pk_mul_f16 %0, %1, %2" : "=v"(r) : "v"(a), "v"(b)); return r;
}
static __device__ inline unsigned pk_max(unsigned a, unsigned b) {
    unsigned r; asm("v_pk_max_f16 %0, %1, %2" : "=v"(r) : "v"(a), "v"(b)); return r;
}

// ---------------------------------------------------------------------------
// Kernel 1: per-point precompute. Feats tile in LDS (coalesced fill,
// conflict-free strided reads); weights read via wave-uniform loads -> s_load
// (constant cache), keeping both the LDS pipe and VMEM lanes quiet.
//   packN[j] (96 B) = { x,y,z,Mdot (f32) | Bn'[0..7] (f16) | G[0..31] (f16) }
//   packC[j] (48 B) = { x,y,z,etadot (f32) | A'[0..7] (f32) }
// ---------------------------------------------------------------------------
__global__ __launch_bounds__(256) void k1_precompute(
    const float* __restrict__ feats,   // [TOTAL][35]
    const float* __restrict__ pW,      // point_W  [10][8]
    const float* __restrict__ pBN,     // point_bn [4][8]
    const float* __restrict__ eW,      // eta_W    [32][8]
    const float* __restrict__ eBN,     // eta_bn   [4][8]
    const float* __restrict__ mW,      // mu_W     [32][8]
    const float* __restrict__ mBN,     // mu_bn    [4][8]
    const float* __restrict__ gW,      // gamma_W  [35][32]
    const float* __restrict__ gBN,     // gamma_bn [4][32]
    const float* __restrict__ mapW,    // map_W    [24]
    float* __restrict__ packN,
    float* __restrict__ packC)
{
    __shared__ float sF[256 * 35];     // feats tile, 35 KB

    const int tid = threadIdx.x;
    const int base = blockIdx.x * 256;

#pragma unroll
    for (int t = 0; t < 35; ++t)
        sF[t * 256 + tid] = feats[(size_t)base * 35 + t * 256 + tid];
    __syncthreads();

    const float* f = sF + tid * 35;    // bank-stride 3 across lanes: 2-way, free
    const float x = f[0], y = f[1], z = f[2];
    const float pp = x * x + y * y + z * z;

    // ---- G = bn(f @ gamma_W) : weights via uniform (s_load) ------------
    float G[32];
#pragma unroll
    for (int q = 0; q < 32; ++q) G[q] = 0.f;
#pragma unroll 4
    for (int d = 0; d < 35; ++d) {
        const float fd = f[d];
        const float4* w4 = (const float4*)(gW + d * 32);   // wave-uniform
#pragma unroll
        for (int q4 = 0; q4 < 8; ++q4) {
            const float4 w = w4[q4];
            G[q4 * 4 + 0] = fmaf(fd, w.x, G[q4 * 4 + 0]);
            G[q4 * 4 + 1] = fmaf(fd, w.y, G[q4 * 4 + 1]);
            G[q4 * 4 + 2] = fmaf(fd, w.z, G[q4 * 4 + 2]);
            G[q4 * 4 + 3] = fmaf(fd, w.w, G[q4 * 4 + 3]);
        }
    }
#pragma unroll
    for (int q = 0; q < 32; ++q) {
        const float g = gBN[q], b = gBN[32 + q], m = gBN[64 + q], v = gBN[96 + q];
        const float s = g / sqrtf(v + EPSB);
        G[q] = fmaf(G[q], s, b - m * s);
    }

    // ---- eta / mu (8ch) -> scalar dots with map_W ----------------------
    float eta[8], mu[8];
#pragma unroll
    for (int q = 0; q < 8; ++q) { eta[q] = 0.f; mu[q] = 0.f; }
#pragma unroll 4
    for (int i = 0; i < 32; ++i) {
        const float fi = f[3 + i];
        const float4* e4 = (const float4*)(eW + i * 8);    // wave-uniform
        const float4* m4 = (const float4*)(mW + i * 8);
#pragma unroll
        for (int h = 0; h < 2; ++h) {
            const float4 we = e4[h], wm = m4[h];
            eta[h * 4 + 0] = fmaf(fi, we.x, eta[h * 4 + 0]);
            eta[h * 4 + 1] = fmaf(fi, we.y, eta[h * 4 + 1]);
            eta[h * 4 + 2] = fmaf(fi, we.z, eta[h * 4 + 2]);
            eta[h * 4 + 3] = fmaf(fi, we.w, eta[h * 4 + 3]);
            mu[h * 4 + 0] = fmaf(fi, wm.x, mu[h * 4 + 0]);
            mu[h * 4 + 1] = fmaf(fi, wm.y, mu[h * 4 + 1]);
            mu[h * 4 + 2] = fmaf(fi, wm.z, mu[h * 4 + 2]);
            mu[h * 4 + 3] = fmaf(fi, wm.w, mu[h * 4 + 3]);
        }
    }
    float etadot = 0.f, Mdot = 0.f;
#pragma unroll
    for (int q = 0; q < 8; ++q) {
        const float ge = eBN[q], be = eBN[8 + q], me = eBN[16 + q], ve = eBN[24 + q];
        const float se = ge / sqrtf(ve + EPSB);
        etadot = fmaf(fmaf(eta[q], se, be - me * se), mapW[8 + q], etadot);
        const float gm = mBN[q], bm = mBN[8 + q], mm = mBN[16 + q], vm = mBN[24 + q];
        const float sm = gm / sqrtf(vm + EPSB);
        Mdot = fmaf(fmaf(mu[q], sm, bm - mm * sm), mapW[16 + q], Mdot);
    }

    // ---- point branch split: neighbor part Bn', center part A' ---------
    float Bnp[8], Ap[8];
#pragma unroll
    for (int q = 0; q < 8; ++q) {
        const float pw0 = pW[q];
        const float g = pBN[q], b = pBN[8 + q], m = pBN[16 + q], v = pBN[24 + q];
        const float s = g / sqrtf(v + EPSB);
        const float t = b - m * s;
        const float Braw = pp * pw0
            + x * (pW[32 + q] - pW[56 + q])
            + y * (pW[40 + q] - pW[64 + q])
            + z * (pW[48 + q] - pW[72 + q]);
        const float Araw = pp * pw0
            + x * (pW[8 + q]  + pW[56 + q])
            + y * (pW[16 + q] + pW[64 + q])
            + z * (pW[24 + q] + pW[72 + q]);
        Bnp[q] = Braw * s;
        Ap[q]  = fmaf(Araw, s, t);
    }

    // ---- stores --------------------------------------------------------
    const int j = base + tid;
    float4* PN = (float4*)(packN + (size_t)j * NPACK);
    PN[0] = make_float4(x, y, z, Mdot);
    {
        float4 b4;
        __half2* hb = (__half2*)&b4;
        hb[0] = __floats2half2_rn(Bnp[0], Bnp[1]);
        hb[1] = __floats2half2_rn(Bnp[2], Bnp[3]);
        hb[2] = __floats2half2_rn(Bnp[4], Bnp[5]);
        hb[3] = __floats2half2_rn(Bnp[6], Bnp[7]);
        PN[1] = b4;
    }
#pragma unroll
    for (int q = 0; q < 4; ++q) {
        float4 g4;
        __half2* hg = (__half2*)&g4;
        hg[0] = __floats2half2_rn(G[q * 8 + 0], G[q * 8 + 1]);
        hg[1] = __floats2half2_rn(G[q * 8 + 2], G[q * 8 + 3]);
        hg[2] = __floats2half2_rn(G[q * 8 + 4], G[q * 8 + 5]);
        hg[3] = __floats2half2_rn(G[q * 8 + 6], G[q * 8 + 7]);
        PN[2 + q] = g4;
    }

    float4* PC = (float4*)(packC + (size_t)j * CPACK);
    PC[0] = make_float4(x, y, z, etadot);
    PC[1] = make_float4(Ap[0], Ap[1], Ap[2], Ap[3]);
    PC[2] = make_float4(Ap[4], Ap[5], Ap[6], Ap[7]);
}

// ---------------------------------------------------------------------------
// Kernel 2 (fused): gather + gate + packed-f16 max-pool + MFMA fc.
// 32 centers/block, 8 lanes/center (2 gathers each), pooled tile bf16 in LDS
// (2560 B, stride 40 shorts = 2-way bank), fc = 4x mfma_f32_16x16x32_bf16
// per wave, D written straight to out.
// ---------------------------------------------------------------------------
__global__ __launch_bounds__(256) void k2_aggregate_fc(
    const int* __restrict__ idx,      // [TOTAL][16]
    const float* __restrict__ packN,
    const float* __restrict__ packC,
    const float* __restrict__ pW,     // point_W
    const float* __restrict__ pBN,    // point_bn
    const float* __restrict__ mapW,   // [24]
    const float* __restrict__ mapBN,  // [4]
    const float* __restrict__ fcW,    // [32][128]
    float* __restrict__ out)          // [TOTAL][128]
{
    __shared__ __align__(16) unsigned short sPool[32 * 40];  // bf16 pooled tile

    const int tid  = threadIdx.x;
    const int cl   = tid >> 3;        // local center 0..31
    const int ks   = tid & 7;         // 8-lane group slot
    const int cbase = blockIdx.x * 32;
    const int c    = cbase + cl;
    const int lane = tid & 63;
    const int w    = tid >> 6;        // wave 0..3
    const int lm   = lane & 15, lq = lane >> 4;

    // ---- B fragments (fcW -> bf16), k = 8*lq + j, col = nt*16 + lm -----
    short8 bfrag[2];
#pragma unroll
    for (int ntj = 0; ntj < 2; ++ntj) {
        const int nt = 2 * w + ntj;
#pragma unroll
        for (int j = 0; j < 8; ++j)
            bfrag[ntj][j] = f2bf(fcW[(8 * lq + j) * 128 + nt * 16 + lm]);
    }

    // ---- gate constants ------------------------------------------------
    float ms, mt;
    {
        const float g = mapBN[0], b = mapBN[1], m = mapBN[2], v = mapBN[3];
        ms = g / sqrtf(v + EPSB);
        mt = b - m * ms;
    }
    float W0p[8], mW0[8];
#pragma unroll
    for (int q = 0; q < 8; ++q) {
        const float g = pBN[q], v = pBN[24 + q];
        const float s = g / sqrtf(v + EPSB);
        W0p[q] = 2.f * pW[q] * s;
        mW0[q] = mapW[q];
    }

    const float4* PC = (const float4*)(packC + (size_t)c * CPACK);
    const float4 c0 = PC[0], c1 = PC[1], c2 = PC[2];
    const float px = c0.x, py = c0.y, pz = c0.z, etadot = c0.w;
    const float Ap[8] = { c1.x, c1.y, c1.z, c1.w, c2.x, c2.y, c2.z, c2.w };

    const int2 ib2 = ((const int2*)idx)[c * 8 + ks];
    const int nbr[2] = { ib2.x, ib2.y };
    const int bbase = c & ~(N_PTS - 1);   // b * N

    unsigned o16[16];                  // packed-f16 channel pairs
#pragma unroll
    for (int q = 0; q < 16; ++q) o16[q] = 0xFC00FC00u;   // (-inf, -inf)

#pragma unroll
    for (int k = 0; k < 2; ++k) {
        const int gj = bbase + nbr[k];
        const float4* P = (const float4*)(packN + (size_t)gj * NPACK);
        const float4 h  = P[0];           // x, y, z, Mdot
        const float4 b4 = P[1];
        const float4 g0 = P[2], g1 = P[3], g2 = P[4], g3 = P[5];

        const float dot3 = px * h.x + py * h.y + pz * h.z;
        const __half2* hb = (const __half2*)&b4;
        float pd = 0.f;
#pragma unroll
        for (int q = 0; q < 4; ++q) {
            const float2 bn2 = __half22float2(hb[q]);
            const float u0 = Ap[2 * q]     + bn2.x - dot3 * W0p[2 * q];
            const float u1 = Ap[2 * q + 1] + bn2.y - dot3 * W0p[2 * q + 1];
            pd = fmaf(fmaxf(u0, 0.f), mW0[2 * q], pd);
            pd = fmaf(fmaxf(u1, 0.f), mW0[2 * q + 1], pd);
        }
        float s = fmaf(pd + etadot + h.w, ms, mt);
        s = fmaxf(s, 0.f);

        const unsigned short su = __half_as_ushort(__float2half_rn(s));
        const unsigned s2 = (unsigned)su * 0x10001u;      // (s, s) packed

        const float4 gs[4] = { g0, g1, g2, g3 };
#pragma unroll
        for (int q = 0; q < 4; ++q) {
            const unsigned* hg = (const unsigned*)&gs[q];
#pragma unroll
            for (int r = 0; r < 4; ++r)
                o16[q * 4 + r] = pk_max(o16[q * 4 + r], pk_mul(s2, hg[r]));
        }
    }

    // ---- 3-level packed max reduce across the 8-lane group -------------
#pragma unroll
    for (int q = 0; q < 16; ++q) {
        unsigned v = o16[q];
        v = pk_max(v, (unsigned)__shfl_xor((int)v, 1));
        v = pk_max(v, (unsigned)__shfl_xor((int)v, 2));
        v = pk_max(v, (unsigned)__shfl_xor((int)v, 4));
        o16[q] = v;
    }

    // lane ks owns channels 4ks..4ks+3: f16 -> bf16, one 8 B store --------
    {
        const unsigned v0 = o16[2 * ks], v1 = o16[2 * ks + 1];
        const float c0f = __half2float(__ushort_as_half((unsigned short)(v0 & 0xffff)));
        const float c1f = __half2float(__ushort_as_half((unsigned short)(v0 >> 16)));
        const float c2f = __half2float(__ushort_as_half((unsigned short)(v1 & 0xffff)));
        const float c3f = __half2float(__ushort_as_half((unsigned short)(v1 >> 16)));
        uint2 pk;
        pk.x = (unsigned short)f2bf(c0f) | ((unsigned)(unsigned short)f2bf(c1f) << 16);
        pk.y = (unsigned short)f2bf(c2f) | ((unsigned)(unsigned short)f2bf(c3f) << 16);
        *(uint2*)(sPool + cl * 40 + ks * 4) = pk;
    }
    __syncthreads();

    // ---- fc via MFMA: D[32x32cols per wave] = pooled(32x32) @ fcW ------
    f32x4 acc[2][2];
#pragma unroll
    for (int a = 0; a < 2; ++a)
#pragma unroll
        for (int b = 0; b < 2; ++b)
            acc[a][b] = (f32x4){0.f, 0.f, 0.f, 0.f};

#pragma unroll
    for (int mtile = 0; mtile < 2; ++mtile) {
        const short8 afrag = *(const short8*)(sPool + (mtile * 16 + lm) * 40 + lq * 8);
#pragma unroll
        for (int ntj = 0; ntj < 2; ++ntj)
            acc[mtile][ntj] = __builtin_amdgcn_mfma_f32_16x16x32_bf16(
                afrag, bfrag[ntj], acc[mtile][ntj], 0, 0, 0);
    }

#pragma unroll
    for (int mtile = 0; mtile < 2; ++mtile)
#pragma unroll
        for (int ntj = 0; ntj < 2; ++ntj) {
            const int nt = 2 * w + ntj;
#pragma unroll
            for (int r = 0; r < 4; ++r)
                out[(size_t)(cbase + mtile * 16 + lq * 4 + r) * 128 + nt * 16 + lm] =
                    acc[mtile][ntj][r];
        }
}

// ---------------------------------------------------------------------------
extern "C" void kernel_launch(void* const* d_in, const int* in_sizes, int n_in,
                              void* d_out, int out_size, void* d_ws, size_t ws_size,
                              hipStream_t stream) {
    const float* feats    = (const float*)d_in[0];
    const int*   idx      = (const int*)  d_in[1];
    const float* point_W  = (const float*)d_in[2];
    const float* point_bn = (const float*)d_in[3];
    const float* eta_W    = (const float*)d_in[4];
    const float* eta_bn   = (const float*)d_in[5];
    const float* mu_W     = (const float*)d_in[6];
    const float* mu_bn    = (const float*)d_in[7];
    const float* gamma_W  = (const float*)d_in[8];
    const float* gamma_bn = (const float*)d_in[9];
    const float* map_W    = (const float*)d_in[10];
    const float* map_bn   = (const float*)d_in[11];
    const float* fc_W     = (const float*)d_in[12];
    float* out = (float*)d_out;

    float* packN  = (float*)d_ws;                  // TOTAL*24 f = 12.6 MB
    float* packC  = packN + (size_t)TOTAL * NPACK; // TOTAL*12 f =  6.3 MB

    hipLaunchKernelGGL(k1_precompute, dim3(TOTAL / 256), dim3(256), 0, stream,
                       feats, point_W, point_bn, eta_W, eta_bn, mu_W, mu_bn,
                       gamma_W, gamma_bn, map_W, packN, packC);
    hipLaunchKernelGGL(k2_aggregate_fc, dim3(TOTAL / 32), dim3(256), 0, stream,
                       idx, packN, packC, point_W, point_bn, map_W, map_bn,
                       fc_W, out);
}

// Round 8
// 161.515 us; speedup vs baseline: 1.8429x; 1.0961x over previous
//
#include <hip/hip_runtime.h>
#include <hip/hip_fp16.h>
#include <math.h>

#define N_PTS   65536
#define BATCH   2
#define TOTAL   (BATCH * N_PTS)   // 131072
#define NPACK_DW 16               // dwords per point, neighbor payload (64 B)
#define CPACK   12                // floats per point, center payload
#define EPSB    1e-5f

typedef float  f32x4  __attribute__((ext_vector_type(4)));
typedef _Float16 f16x8 __attribute__((ext_vector_type(8)));

static __device__ inline unsigned h2u(float a, float b) {
    __half2 h = __floats2half2_rn(a, b);
    union { __half2 h; unsigned u; } cv; cv.h = h; return cv.u;
}
static __device__ inline float2 u2f2(unsigned u) {
    union { unsigned u; __half2 h; } cv; cv.u = u; return __half22float2(cv.h);
}
static __device__ inline unsigned pk_max(unsigned a, unsigned b) {
    unsigned r; asm("v_pk_max_f16 %0, %1, %2" : "=v"(r) : "v"(a), "v"(b)); return r;
}

// ---------------------------------------------------------------------------
// Kernel 1: per-point precompute (R4 structure: LDS-staged weights + feats).
//   packN[j] (64 B dwords):
//     0: h(x,y)  1: h(z,Mdot)  2-5: h(Bn0..7)
//     6-13: G quantized u8 = rint(127*G/scale)+128
//     14: scale = max|G| (f32 bits)   15: pad
//   packC[j] (48 B) = { x,y,z,etadot (f32) | A'[0..7] (f32) }
// ---------------------------------------------------------------------------
__global__ __launch_bounds__(256) void k1_precompute(
    const float* __restrict__ feats,   // [TOTAL][35]
    const float* __restrict__ pW,      // point_W  [10][8]
    const float* __restrict__ pBN,     // point_bn [4][8]
    const float* __restrict__ eW,      // eta_W    [32][8]
    const float* __restrict__ eBN,     // eta_bn   [4][8]
    const float* __restrict__ mW,      // mu_W     [32][8]
    const float* __restrict__ mBN,     // mu_bn    [4][8]
    const float* __restrict__ gW,      // gamma_W  [35][32]
    const float* __restrict__ gBN,     // gamma_bn [4][32]
    const float* __restrict__ mapW,    // map_W    [24]
    unsigned* __restrict__ packN,
    float* __restrict__ packC)
{
    __shared__ float sG[35 * 32];      // gamma_W
    __shared__ float sE[32 * 8];       // eta_W
    __shared__ float sM[32 * 8];       // mu_W
    __shared__ float sF[256 * 35];     // feats tile

    const int tid = threadIdx.x;
    const int base = blockIdx.x * 256;

    for (int i = tid; i < 35 * 32; i += 256) sG[i] = gW[i];
    sE[tid] = eW[tid]; sM[tid] = mW[tid];
#pragma unroll
    for (int t = 0; t < 35; ++t)
        sF[t * 256 + tid] = feats[(size_t)base * 35 + t * 256 + tid];
    __syncthreads();

    const float* f = sF + tid * 35;    // bank-stride 3 across lanes: 2-way, free
    const float x = f[0], y = f[1], z = f[2];
    const float pp = x * x + y * y + z * z;

    // ---- G = bn(f @ gamma_W) -------------------------------------------
    float G[32];
#pragma unroll
    for (int q = 0; q < 32; ++q) G[q] = 0.f;
#pragma unroll 4
    for (int d = 0; d < 35; ++d) {
        const float fd = f[d];
        const float4* w4 = (const float4*)(sG + d * 32);  // broadcast reads
#pragma unroll
        for (int q4 = 0; q4 < 8; ++q4) {
            const float4 w = w4[q4];
            G[q4 * 4 + 0] = fmaf(fd, w.x, G[q4 * 4 + 0]);
            G[q4 * 4 + 1] = fmaf(fd, w.y, G[q4 * 4 + 1]);
            G[q4 * 4 + 2] = fmaf(fd, w.z, G[q4 * 4 + 2]);
            G[q4 * 4 + 3] = fmaf(fd, w.w, G[q4 * 4 + 3]);
        }
    }
#pragma unroll
    for (int q = 0; q < 32; ++q) {
        const float g = gBN[q], b = gBN[32 + q], m = gBN[64 + q], v = gBN[96 + q];
        const float s = g / sqrtf(v + EPSB);
        G[q] = fmaf(G[q], s, b - m * s);
    }

    // ---- eta / mu (8ch) -> scalar dots with map_W ----------------------
    float eta[8], mu[8];
#pragma unroll
    for (int q = 0; q < 8; ++q) { eta[q] = 0.f; mu[q] = 0.f; }
#pragma unroll 4
    for (int i = 0; i < 32; ++i) {
        const float fi = f[3 + i];
        const float4* e4 = (const float4*)(sE + i * 8);
        const float4* m4 = (const float4*)(sM + i * 8);
#pragma unroll
        for (int h = 0; h < 2; ++h) {
            const float4 we = e4[h], wm = m4[h];
            eta[h * 4 + 0] = fmaf(fi, we.x, eta[h * 4 + 0]);
            eta[h * 4 + 1] = fmaf(fi, we.y, eta[h * 4 + 1]);
            eta[h * 4 + 2] = fmaf(fi, we.z, eta[h * 4 + 2]);
            eta[h * 4 + 3] = fmaf(fi, we.w, eta[h * 4 + 3]);
            mu[h * 4 + 0] = fmaf(fi, wm.x, mu[h * 4 + 0]);
            mu[h * 4 + 1] = fmaf(fi, wm.y, mu[h * 4 + 1]);
            mu[h * 4 + 2] = fmaf(fi, wm.z, mu[h * 4 + 2]);
            mu[h * 4 + 3] = fmaf(fi, wm.w, mu[h * 4 + 3]);
        }
    }
    float etadot = 0.f, Mdot = 0.f;
#pragma unroll
    for (int q = 0; q < 8; ++q) {
        const float ge = eBN[q], be = eBN[8 + q], me = eBN[16 + q], ve = eBN[24 + q];
        const float se = ge / sqrtf(ve + EPSB);
        etadot = fmaf(fmaf(eta[q], se, be - me * se), mapW[8 + q], etadot);
        const float gm = mBN[q], bm = mBN[8 + q], mm = mBN[16 + q], vm = mBN[24 + q];
        const float sm = gm / sqrtf(vm + EPSB);
        Mdot = fmaf(fmaf(mu[q], sm, bm - mm * sm), mapW[16 + q], Mdot);
    }

    // ---- point branch split: neighbor part Bn', center part A' ---------
    float Bnp[8], Ap[8];
#pragma unroll
    for (int q = 0; q < 8; ++q) {
        const float pw0 = pW[q];
        const float g = pBN[q], b = pBN[8 + q], m = pBN[16 + q], v = pBN[24 + q];
        const float s = g / sqrtf(v + EPSB);
        const float t = b - m * s;
        const float Braw = pp * pw0
            + x * (pW[32 + q] - pW[56 + q])
            + y * (pW[40 + q] - pW[64 + q])
            + z * (pW[48 + q] - pW[72 + q]);
        const float Araw = pp * pw0
            + x * (pW[8 + q]  + pW[56 + q])
            + y * (pW[16 + q] + pW[64 + q])
            + z * (pW[24 + q] + pW[72 + q]);
        Bnp[q] = Braw * s;
        Ap[q]  = fmaf(Araw, s, t);
    }

    // ---- stores: 64 B packN, G as int8 + per-point scale ----------------
    const int j = base + tid;
    float gmax = 0.f;
#pragma unroll
    for (int q = 0; q < 32; ++q) gmax = fmaxf(gmax, fabsf(G[q]));
    const float inv = (gmax > 0.f) ? (127.f / gmax) : 0.f;
    unsigned gq[8];
#pragma unroll
    for (int qd = 0; qd < 8; ++qd) {
        unsigned d = 0;
#pragma unroll
        for (int b = 0; b < 4; ++b) {
            const int q8 = (int)rintf(G[4 * qd + b] * inv) + 128;  // 1..255
            d |= ((unsigned)q8 & 0xffu) << (8 * b);
        }
        gq[qd] = d;
    }
    union { float f; unsigned u; } sc; sc.f = gmax;

    uint4* PN = (uint4*)(packN + (size_t)j * NPACK_DW);
    PN[0] = make_uint4(h2u(x, y), h2u(z, Mdot), h2u(Bnp[0], Bnp[1]), h2u(Bnp[2], Bnp[3]));
    PN[1] = make_uint4(h2u(Bnp[4], Bnp[5]), h2u(Bnp[6], Bnp[7]), gq[0], gq[1]);
    PN[2] = make_uint4(gq[2], gq[3], gq[4], gq[5]);
    PN[3] = make_uint4(gq[6], gq[7], sc.u, 0u);

    float4* PC = (float4*)(packC + (size_t)j * CPACK);
    PC[0] = make_float4(x, y, z, etadot);
    PC[1] = make_float4(Ap[0], Ap[1], Ap[2], Ap[3]);
    PC[2] = make_float4(Ap[4], Ap[5], Ap[6], Ap[7]);
}

// ---------------------------------------------------------------------------
// Kernel 2 (fused): gather + gate + packed-f16 max-pool + f16 MFMA fc.
// 32 centers/block, 8 lanes/center, 2 gathers/lane (4x uint4 each).
// XCD-batch affinity swizzle keeps each XCD's L2 on one batch's 4 MiB pool.
// ---------------------------------------------------------------------------
__global__ __launch_bounds__(256) void k2_aggregate_fc(
    const int* __restrict__ idx,      // [TOTAL][16] (int32 on device)
    const unsigned* __restrict__ packN,
    const float* __restrict__ packC,
    const float* __restrict__ pW,     // point_W
    const float* __restrict__ pBN,    // point_bn
    const float* __restrict__ mapW,   // [24]
    const float* __restrict__ mapBN,  // [4]
    const float* __restrict__ fcW,    // [32][128]
    float* __restrict__ out)          // [TOTAL][128]
{
    __shared__ __align__(16) unsigned short sPool[32 * 40];  // f16 pooled tile

    // ---- XCD-batch affinity remap (grid = 4096, 8 XCDs round-robin) ----
    const int bid  = blockIdx.x;
    const int xcd  = bid & 7, slot = bid >> 3;           // slot 0..511
    const int cb   = (xcd < 4) ? (slot * 4 + xcd)
                               : (2048 + slot * 4 + (xcd - 4));
    const int cbase = cb * 32;

    const int tid  = threadIdx.x;
    const int cl   = tid >> 3;        // local center 0..31
    const int ks   = tid & 7;         // 8-lane group slot
    const int c    = cbase + cl;
    const int lane = tid & 63;
    const int w    = tid >> 6;        // wave 0..3
    const int lm   = lane & 15, lq = lane >> 4;

    // ---- B fragments (fcW -> f16), k = 8*lq + j, col = nt*16 + lm ------
    f16x8 bfrag[2];
#pragma unroll
    for (int ntj = 0; ntj < 2; ++ntj) {
        const int nt = 2 * w + ntj;
        union { unsigned short u[8]; f16x8 v; } cv;
#pragma unroll
        for (int j = 0; j < 8; ++j)
            cv.u[j] = __half_as_ushort(__float2half_rn(fcW[(8 * lq + j) * 128 + nt * 16 + lm]));
        bfrag[ntj] = cv.v;
    }

    // ---- gate constants ------------------------------------------------
    float ms, mt;
    {
        const float g = mapBN[0], b = mapBN[1], m = mapBN[2], v = mapBN[3];
        ms = g / sqrtf(v + EPSB);
        mt = b - m * ms;
    }
    float W0p[8], mW0[8];
#pragma unroll
    for (int q = 0; q < 8; ++q) {
        const float g = pBN[q], v = pBN[24 + q];
        const float s = g / sqrtf(v + EPSB);
        W0p[q] = 2.f * pW[q] * s;
        mW0[q] = mapW[q];
    }

    const float4* PC = (const float4*)(packC + (size_t)c * CPACK);
    const float4 c0 = PC[0], c1 = PC[1], c2 = PC[2];
    const float px = c0.x, py = c0.y, pz = c0.z, etadot = c0.w;
    const float Ap[8] = { c1.x, c1.y, c1.z, c1.w, c2.x, c2.y, c2.z, c2.w };

    const int2 ib2 = ((const int2*)idx)[c * 8 + ks];
    const int bbase = c & ~(N_PTS - 1);   // b * N

    unsigned o16[16];                  // packed-f16 channel pairs
#pragma unroll
    for (int q = 0; q < 16; ++q) o16[q] = 0xFC00FC00u;   // (-inf, -inf)

    // issue both gathers' loads up-front
    const uint4* P0 = (const uint4*)(packN + (size_t)(bbase + ib2.x) * NPACK_DW);
    const uint4* P1 = (const uint4*)(packN + (size_t)(bbase + ib2.y) * NPACK_DW);
    uint4 n0[4] = { P0[0], P0[1], P0[2], P0[3] };
    uint4 n1[4] = { P1[0], P1[1], P1[2], P1[3] };

#pragma unroll
    for (int k = 0; k < 2; ++k) {
        const uint4* N = k ? n1 : n0;
        const float2 xy = u2f2(N[0].x), zM = u2f2(N[0].y);
        const float dot3 = px * xy.x + py * xy.y + pz * zM.x;

        const unsigned bn[4] = { N[0].z, N[0].w, N[1].x, N[1].y };
        float pd = 0.f;
#pragma unroll
        for (int q = 0; q < 4; ++q) {
            const float2 bn2 = u2f2(bn[q]);
            const float u0 = Ap[2 * q]     + bn2.x - dot3 * W0p[2 * q];
            const float u1 = Ap[2 * q + 1] + bn2.y - dot3 * W0p[2 * q + 1];
            pd = fmaf(fmaxf(u0, 0.f), mW0[2 * q], pd);
            pd = fmaf(fmaxf(u1, 0.f), mW0[2 * q + 1], pd);
        }
        float s = fmaf(pd + etadot + zM.y, ms, mt);
        s = fmaxf(s, 0.f);

        // ---- dequant G (int8 + scale) and fold the gate multiply -------
        union { unsigned u; float f; } sc; sc.u = N[3].z;
        const float t  = s * sc.f * (1.f / 127.f);
        const float nt = -128.f * t;

        const unsigned gd[8] = { N[1].z, N[1].w, N[2].x, N[2].y,
                                 N[2].z, N[2].w, N[3].x, N[3].y };
#pragma unroll
        for (int qd = 0; qd < 8; ++qd) {
            const unsigned dwv = gd[qd];
            const float v0 = fmaf(t, (float)( dwv        & 0xffu), nt);
            const float v1 = fmaf(t, (float)((dwv >>  8) & 0xffu), nt);
            const float v2 = fmaf(t, (float)((dwv >> 16) & 0xffu), nt);
            const float v3 = fmaf(t, (float)( dwv >> 24        ), nt);
            o16[2 * qd]     = pk_max(o16[2 * qd],     h2u(v0, v1));
            o16[2 * qd + 1] = pk_max(o16[2 * qd + 1], h2u(v2, v3));
        }
    }

    // ---- 3-level packed max reduce across the 8-lane group -------------
#pragma unroll
    for (int q = 0; q < 16; ++q) {
        unsigned v = o16[q];
        v = pk_max(v, (unsigned)__shfl_xor((int)v, 1));
        v = pk_max(v, (unsigned)__shfl_xor((int)v, 2));
        v = pk_max(v, (unsigned)__shfl_xor((int)v, 4));
        o16[q] = v;
    }

    // lane ks owns channels 4ks..4ks+3 (f16), one 8 B store ---------------
    {
        uint2 pk;
        pk.x = o16[2 * ks];
        pk.y = o16[2 * ks + 1];
        *(uint2*)(sPool + cl * 40 + ks * 4) = pk;
    }
    __syncthreads();

    // ---- fc via MFMA: D[32 x 32cols per wave] = pooled(32x32) @ fcW ----
    f32x4 acc[2][2];
#pragma unroll
    for (int a = 0; a < 2; ++a)
#pragma unroll
        for (int b = 0; b < 2; ++b)
            acc[a][b] = (f32x4){0.f, 0.f, 0.f, 0.f};

#pragma unroll
    for (int mtile = 0; mtile < 2; ++mtile) {
        const f16x8 afrag = *(const f16x8*)(sPool + (mtile * 16 + lm) * 40 + lq * 8);
#pragma unroll
        for (int ntj = 0; ntj < 2; ++ntj)
            acc[mtile][ntj] = __builtin_amdgcn_mfma_f32_16x16x32_f16(
                afrag, bfrag[ntj], acc[mtile][ntj], 0, 0, 0);
    }

#pragma unroll
    for (int mtile = 0; mtile < 2; ++mtile)
#pragma unroll
        for (int ntj = 0; ntj < 2; ++ntj) {
            const int nt = 2 * w + ntj;
#pragma unroll
            for (int r = 0; r < 4; ++r)
                __builtin_nontemporal_store(acc[mtile][ntj][r],
                    &out[(size_t)(cbase + mtile * 16 + lq * 4 + r) * 128 + nt * 16 + lm]);
        }
}

// ---------------------------------------------------------------------------
extern "C" void kernel_launch(void* const* d_in, const int* in_sizes, int n_in,
                              void* d_out, int out_size, void* d_ws, size_t ws_size,
                              hipStream_t stream) {
    const float* feats    = (const float*)d_in[0];
    const int*   idx      = (const int*)  d_in[1];
    const float* point_W  = (const float*)d_in[2];
    const float* point_bn = (const float*)d_in[3];
    const float* eta_W    = (const float*)d_in[4];
    const float* eta_bn   = (const float*)d_in[5];
    const float* mu_W     = (const float*)d_in[6];
    const float* mu_bn    = (const float*)d_in[7];
    const float* gamma_W  = (const float*)d_in[8];
    const float* gamma_bn = (const float*)d_in[9];
    const float* map_W    = (const float*)d_in[10];
    const float* map_bn   = (const float*)d_in[11];
    const float* fc_W     = (const float*)d_in[12];
    float* out = (float*)d_out;

    unsigned* packN = (unsigned*)d_ws;                      // TOTAL*64 B = 8.4 MB
    float*    packC = (float*)(packN + (size_t)TOTAL * NPACK_DW); // 6.3 MB

    hipLaunchKernelGGL(k1_precompute, dim3(TOTAL / 256), dim3(256), 0, stream,
                       feats, point_W, point_bn, eta_W, eta_bn, mu_W, mu_bn,
                       gamma_W, gamma_bn, map_W, packN, packC);
    hipLaunchKernelGGL(k2_aggregate_fc, dim3(TOTAL / 32), dim3(256), 0, stream,
                       idx, packN, packC, point_W, point_bn, map_W, map_bn,
                       fc_W, out);
}